// Round 3
// baseline (2601.618 us; speedup 1.0000x reference)
//
#include <hip/hip_runtime.h>
#include <hip/hip_bf16.h>
#include <stdint.h>

// ---------------- CSR build ----------------

__global__ __launch_bounds__(256) void histogram_kernel(const int* __restrict__ col,
                                                        int* __restrict__ indeg, int E) {
    int i = blockIdx.x * 256 + threadIdx.x;
    if (i < E) atomicAdd(&indeg[col[i]], 1);
}

__global__ __launch_bounds__(256) void dinv_kernel(const int* __restrict__ indeg,
                                                   float* __restrict__ dinv, int N) {
    int i = blockIdx.x * 256 + threadIdx.x;
    if (i < N) dinv[i] = rsqrtf((float)(indeg[i] + 1));  // +1 self-loop; deg>=1 always
}

// Block-wide (256 threads) exclusive scan helper. Returns exclusive prefix of v.
__device__ __forceinline__ int block_excl_scan_256(int v, int tid) {
    int lane = tid & 63, wid = tid >> 6;
    int x = v;
    #pragma unroll
    for (int o = 1; o < 64; o <<= 1) {
        int y = __shfl_up(x, o, 64);
        if (lane >= o) x += y;
    }
    __shared__ int wsum[4];
    if (lane == 63) wsum[wid] = x;
    __syncthreads();
    int base = 0;
    #pragma unroll
    for (int j = 0; j < 4; j++) base += (j < wid) ? wsum[j] : 0;
    return base + x - v;
}

// k1: per-block (256-elem chunk) sums of indeg
__global__ __launch_bounds__(256) void blocksum_kernel(const int* __restrict__ cnt,
                                                       int* __restrict__ bsum, int N) {
    int tid = threadIdx.x;
    int i = blockIdx.x * 256 + tid;
    int v = (i < N) ? cnt[i] : 0;
    int lane = tid & 63, wid = tid >> 6;
    #pragma unroll
    for (int o = 32; o > 0; o >>= 1) v += __shfl_down(v, o, 64);
    __shared__ int ws[4];
    if (lane == 0) ws[wid] = v;
    __syncthreads();
    if (tid == 0) bsum[blockIdx.x] = ws[0] + ws[1] + ws[2] + ws[3];
}

// k2: exclusive scan of bsum[nb] in place (nb <= 256), one block
__global__ __launch_bounds__(256) void scan_bsums_kernel(int* __restrict__ bsum, int nb) {
    int tid = threadIdx.x;
    int v = (tid < nb) ? bsum[tid] : 0;
    int ex = block_excl_scan_256(v, tid);
    if (tid < nb) bsum[tid] = ex;   // writes happen after the scan's internal sync
}

// k3: final offsets: off[i] = bsumExcl[blk] + local exclusive scan; off[N] = E
__global__ __launch_bounds__(256) void scan_final_kernel(const int* __restrict__ cnt,
                                                         const int* __restrict__ bexcl,
                                                         int* __restrict__ off, int N, int E) {
    int tid = threadIdx.x;
    int i = blockIdx.x * 256 + tid;
    int v = (i < N) ? cnt[i] : 0;
    int ex = block_excl_scan_256(v, tid);
    if (i < N) off[i] = bexcl[blockIdx.x] + ex;
    if (blockIdx.x == 0 && tid == 0) off[N] = E;
}

__global__ __launch_bounds__(256) void scatter_csr_kernel(const int* __restrict__ row,
                                                          const int* __restrict__ col,
                                                          const int* __restrict__ off,
                                                          int* __restrict__ fill,
                                                          int* __restrict__ srclist, int E) {
    int i = blockIdx.x * 256 + threadIdx.x;
    if (i < E) {
        int c = col[i];
        int p = atomicAdd(&fill[c], 1);
        srclist[off[c] + p] = row[i];
    }
}

// ---------------- GEMM: out[n][:] = (X[n][:] @ W) * dinv[n] ----------------
// Block: 32 rows x 128 cols, 256 threads, thread = 4 rows x 4 cols.
// X tile staged in LDS (16 KB); W read directly from global (64 KB, L1/L2-broadcast).
__global__ __launch_bounds__(256, 4) void gemm_scale_kernel(const float* __restrict__ X,
                                                            const float* __restrict__ W,
                                                            const float* __restrict__ dinv,
                                                            float* __restrict__ out, int N) {
    __shared__ float xs[32 * 128];   // 16 KB
    int tid = threadIdx.x;
    int rowbase = blockIdx.x * 32;

    {   // stage X tile (guarded, zero-fill OOB rows)
        const float4* Xv = (const float4*)(X + (size_t)rowbase * 128);
        float4* xsv = (float4*)xs;
        float4 z = make_float4(0.f, 0.f, 0.f, 0.f);
        #pragma unroll
        for (int j = 0; j < 4; j++) {
            int i = tid + j * 256;               // float4 index within tile
            int r = rowbase + (i >> 5);
            xsv[i] = (r < N) ? Xv[i] : z;
        }
    }
    __syncthreads();

    int cg = tid & 31;   // col group (4 cols)
    int rq = tid >> 5;   // row quad (4 rows)
    const float4* Wv = (const float4*)W;   // W[k][cg*4..] = Wv[k*32+cg]
    float acc[4][4] = {};

    for (int k = 0; k < 128; k += 4) {
        float4 a[4];
        #pragma unroll
        for (int r = 0; r < 4; r++) a[r] = *(const float4*)&xs[(rq * 4 + r) * 128 + k];
        #pragma unroll
        for (int kk = 0; kk < 4; kk++) {
            float4 b = Wv[(k + kk) * 32 + cg];
            #pragma unroll
            for (int r = 0; r < 4; r++) {
                float av = (kk == 0) ? a[r].x : (kk == 1) ? a[r].y : (kk == 2) ? a[r].z : a[r].w;
                acc[r][0] = fmaf(av, b.x, acc[r][0]);
                acc[r][1] = fmaf(av, b.y, acc[r][1]);
                acc[r][2] = fmaf(av, b.z, acc[r][2]);
                acc[r][3] = fmaf(av, b.w, acc[r][3]);
            }
        }
    }

    #pragma unroll
    for (int r = 0; r < 4; r++) {
        int rown = rowbase + rq * 4 + r;
        if (rown < N) {
            float s = dinv[rown];
            float4 o = make_float4(acc[r][0] * s, acc[r][1] * s, acc[r][2] * s, acc[r][3] * s);
            *(float4*)&out[(size_t)rown * 128 + cg * 4] = o;
        }
    }
}

// ---------------- Aggregation (pull mode): one wave per node ----------------
// out[c][:] = relu(dinv[c] * (hs[c][:] + sum_{r in in(c)} hs[r][:]) + bias)
__global__ __launch_bounds__(256, 4) void aggregate_kernel(const float* __restrict__ hs,
                                                           const int* __restrict__ off,
                                                           const int* __restrict__ srclist,
                                                           const float* __restrict__ dinv,
                                                           const float* __restrict__ bias,
                                                           float* __restrict__ out, int N) {
    int wave = (blockIdx.x * 256 + threadIdx.x) >> 6;
    int lane = threadIdx.x & 63;
    if (wave >= N) return;
    int c = wave;
    float2 a0 = *(const float2*)&hs[(size_t)c * 128 + lane * 2];  // self-loop term
    float2 a1 = make_float2(0.f, 0.f);
    float2 a2 = make_float2(0.f, 0.f);
    float2 a3 = make_float2(0.f, 0.f);
    int s0 = off[c], s1 = off[c + 1];
    int i = s0;
    for (; i + 3 < s1; i += 4) {   // 4-deep gather for memory-level parallelism
        int sa = srclist[i], sb = srclist[i + 1], sc = srclist[i + 2], sd = srclist[i + 3];
        float2 va = *(const float2*)&hs[(size_t)sa * 128 + lane * 2];
        float2 vb = *(const float2*)&hs[(size_t)sb * 128 + lane * 2];
        float2 vc = *(const float2*)&hs[(size_t)sc * 128 + lane * 2];
        float2 vd = *(const float2*)&hs[(size_t)sd * 128 + lane * 2];
        a0.x += va.x; a0.y += va.y;
        a1.x += vb.x; a1.y += vb.y;
        a2.x += vc.x; a2.y += vc.y;
        a3.x += vd.x; a3.y += vd.y;
    }
    for (; i < s1; i++) {
        int sa = srclist[i];
        float2 va = *(const float2*)&hs[(size_t)sa * 128 + lane * 2];
        a0.x += va.x; a0.y += va.y;
    }
    a0.x += a1.x + a2.x + a3.x;
    a0.y += a1.y + a2.y + a3.y;
    float d = dinv[c];
    float2 b = *(const float2*)&bias[lane * 2];
    float2 o;
    o.x = fmaxf(fmaf(a0.x, d, b.x), 0.f);
    o.y = fmaxf(fmaf(a0.y, d, b.y), 0.f);
    *(float2*)&out[(size_t)c * 128 + lane * 2] = o;
}

// ---------------- Mean pool over sorted batch ids ----------------
#define POOL_NODES 512
__global__ __launch_bounds__(128) void pool_kernel(const float* __restrict__ h,
                                                   const int* __restrict__ batch,
                                                   float* __restrict__ sums,
                                                   float* __restrict__ cnt, int N) {
    int t = threadIdx.x;  // feature id
    int n0 = blockIdx.x * POOL_NODES;
    if (n0 >= N) return;
    int n1 = min(n0 + POOL_NODES, N);
    int g = batch[n0];
    float acc = 0.f, c = 0.f;
    for (int n = n0; n < n1; n++) {
        int gn = batch[n];  // broadcast load
        if (gn != g) {      // batch sorted -> few flushes per block
            atomicAdd(&sums[g * 128 + t], acc);
            if (t == 0) atomicAdd(&cnt[g], c);
            acc = 0.f; c = 0.f; g = gn;
        }
        acc += h[(size_t)n * 128 + t];
        c += 1.f;
    }
    atomicAdd(&sums[g * 128 + t], acc);
    if (t == 0) atomicAdd(&cnt[g], c);
}

// ---------------- Head: out[g] = dot(sums[g]/max(cnt,1), Wc) + bc ----------------
__global__ __launch_bounds__(64) void head_kernel(const float* __restrict__ sums,
                                                  const float* __restrict__ cnt,
                                                  const float* __restrict__ Wc,
                                                  const float* __restrict__ bc,
                                                  float* __restrict__ out) {
    int g = blockIdx.x, lane = threadIdx.x;
    float c = fmaxf(cnt[g], 1.f);
    float2 s = *(const float2*)&sums[g * 128 + lane * 2];
    float2 w = *(const float2*)&Wc[lane * 2];
    float v = (s.x * w.x + s.y * w.y) / c;
    #pragma unroll
    for (int o = 32; o > 0; o >>= 1) v += __shfl_down(v, o, 64);
    if (lane == 0) out[g] = v + bc[0];
}

extern "C" void kernel_launch(void* const* d_in, const int* in_sizes, int n_in,
                              void* d_out, int out_size, void* d_ws, size_t ws_size,
                              hipStream_t stream) {
    const float* x    = (const float*)d_in[0];
    const int*   edge = (const int*)d_in[1];   // [2][E], row-major
    const int*   batch= (const int*)d_in[2];
    const float* W1   = (const float*)d_in[3];
    const float* b1   = (const float*)d_in[4];
    const float* W2   = (const float*)d_in[5];
    const float* b2   = (const float*)d_in[6];
    const float* Wc   = (const float*)d_in[7];
    const float* bc   = (const float*)d_in[8];
    float* out = (float*)d_out;

    int N = in_sizes[0] / 128;
    int E = in_sizes[1] / 2;
    const int* row = edge;
    const int* col = edge + E;
    int nb = (N + 255) / 256;   // scan chunks

    // workspace: [indeg N][fill N][sums 8192][cnt 64] | bsum | off | dinv | srclist | bufA | bufB
    char* p = (char*)d_ws;
    int*   indeg   = (int*)p;   p += (size_t)N * 4;
    int*   fill    = (int*)p;   p += (size_t)N * 4;
    float* sums    = (float*)p; p += 64 * 128 * 4;
    float* cntg    = (float*)p; p += 64 * 4;
    size_t zero_bytes = (size_t)(p - (char*)d_ws);
    int*   bsum    = (int*)p;   p += (size_t)((nb + 63) & ~63) * 4;
    int*   off     = (int*)p;   p += (size_t)(N + 1) * 4;
    float* dinv    = (float*)p; p += (size_t)N * 4;
    int*   srclist = (int*)p;   p += (size_t)E * 4;
    p = (char*)(((uintptr_t)p + 511) & ~(uintptr_t)511);
    float* bufA    = (float*)p; p += (size_t)N * 128 * 4;
    float* bufB    = (float*)p;

    hipMemsetAsync(d_ws, 0, zero_bytes, stream);  // indeg, fill, sums, cnt

    histogram_kernel<<<(E + 255) / 256, 256, 0, stream>>>(col, indeg, E);
    dinv_kernel<<<(N + 255) / 256, 256, 0, stream>>>(indeg, dinv, N);
    blocksum_kernel<<<nb, 256, 0, stream>>>(indeg, bsum, N);
    scan_bsums_kernel<<<1, 256, 0, stream>>>(bsum, nb);
    scan_final_kernel<<<nb, 256, 0, stream>>>(indeg, bsum, off, N, E);
    scatter_csr_kernel<<<(E + 255) / 256, 256, 0, stream>>>(row, col, off, fill, srclist, E);

    // Layer 1
    gemm_scale_kernel<<<(N + 31) / 32, 256, 0, stream>>>(x, W1, dinv, bufA, N);
    aggregate_kernel<<<(N + 3) / 4, 256, 0, stream>>>(bufA, off, srclist, dinv, b1, bufB, N);
    // Layer 2
    gemm_scale_kernel<<<(N + 31) / 32, 256, 0, stream>>>(bufB, W2, dinv, bufA, N);
    aggregate_kernel<<<(N + 3) / 4, 256, 0, stream>>>(bufA, off, srclist, dinv, b2, bufB, N);

    // Pool + head
    pool_kernel<<<(N + POOL_NODES - 1) / POOL_NODES, 128, 0, stream>>>(bufB, batch, sums, cntg, N);
    head_kernel<<<64, 64, 0, stream>>>(sums, cntg, Wc, bc, out);
}

// Round 4
// 494.965 us; speedup vs baseline: 5.2562x; 5.2562x over previous
//
#include <hip/hip_runtime.h>
#include <hip/hip_bf16.h>
#include <stdint.h>

// ---------------- CSR build ----------------

__global__ __launch_bounds__(256) void histogram_kernel(const int* __restrict__ col,
                                                        int* __restrict__ indeg, int E) {
    int i = blockIdx.x * 256 + threadIdx.x;
    if (i < E) atomicAdd(&indeg[col[i]], 1);
}

// Block-wide (256 threads) exclusive scan helper. Returns exclusive prefix of v.
__device__ __forceinline__ int block_excl_scan_256(int v, int tid) {
    int lane = tid & 63, wid = tid >> 6;
    int x = v;
    #pragma unroll
    for (int o = 1; o < 64; o <<= 1) {
        int y = __shfl_up(x, o, 64);
        if (lane >= o) x += y;
    }
    __shared__ int wsum[4];
    if (lane == 63) wsum[wid] = x;
    __syncthreads();
    int base = 0;
    #pragma unroll
    for (int j = 0; j < 4; j++) base += (j < wid) ? wsum[j] : 0;
    return base + x - v;
}

// k1: per-block (256-elem chunk) sums of indeg
__global__ __launch_bounds__(256) void blocksum_kernel(const int* __restrict__ cnt,
                                                       int* __restrict__ bsum, int N) {
    int tid = threadIdx.x;
    int i = blockIdx.x * 256 + tid;
    int v = (i < N) ? cnt[i] : 0;
    int lane = tid & 63, wid = tid >> 6;
    #pragma unroll
    for (int o = 32; o > 0; o >>= 1) v += __shfl_down(v, o, 64);
    __shared__ int ws[4];
    if (lane == 0) ws[wid] = v;
    __syncthreads();
    if (tid == 0) bsum[blockIdx.x] = ws[0] + ws[1] + ws[2] + ws[3];
}

// k2: exclusive scan of bsum[nb] in place (nb <= 256), one block
__global__ __launch_bounds__(256) void scan_bsums_kernel(int* __restrict__ bsum, int nb) {
    int tid = threadIdx.x;
    int v = (tid < nb) ? bsum[tid] : 0;
    int ex = block_excl_scan_256(v, tid);
    if (tid < nb) bsum[tid] = ex;
}

// k3: final offsets + dinv: off[i] = bexcl[blk] + local excl scan; dinv = rsqrt(deg+1)
__global__ __launch_bounds__(256) void scan_final_kernel(const int* __restrict__ cnt,
                                                         const int* __restrict__ bexcl,
                                                         int* __restrict__ off,
                                                         float* __restrict__ dinv,
                                                         int N, int E) {
    int tid = threadIdx.x;
    int i = blockIdx.x * 256 + tid;
    int v = (i < N) ? cnt[i] : 0;
    int ex = block_excl_scan_256(v, tid);
    if (i < N) {
        off[i] = bexcl[blockIdx.x] + ex;
        dinv[i] = rsqrtf((float)(v + 1));   // +1 self-loop; deg>=1 always
    }
    if (blockIdx.x == 0 && tid == 0) off[N] = E;
}

__global__ __launch_bounds__(256) void scatter_csr_kernel(const int* __restrict__ row,
                                                          const int* __restrict__ col,
                                                          const int* __restrict__ off,
                                                          int* __restrict__ fill,
                                                          int* __restrict__ srclist, int E) {
    int i = blockIdx.x * 256 + threadIdx.x;
    if (i < E) {
        int c = col[i];
        int p = atomicAdd(&fill[c], 1);
        srclist[off[c] + p] = row[i];
    }
}

// ---------------- GEMM: out[n][:] = (X[n][:] @ W) * dinv[n] ----------------
// Block: 32 rows x 128 cols, 256 threads, thread = 4 rows x 4 cols.
// W staged in LDS in two 64-row chunks (32 KB each); X tile 16 KB. LDS total 48 KB.
// launch_bounds(256,3): 3 blocks/CU (LDS-bound), keep VGPR under control.
__global__ __launch_bounds__(256, 3) void gemm_scale_kernel(const float* __restrict__ X,
                                                            const float* __restrict__ W,
                                                            const float* __restrict__ dinv,
                                                            float* __restrict__ out, int N) {
    __shared__ float ws[64 * 128];   // 32 KB (one K-chunk of W)
    __shared__ float xs[32 * 128];   // 16 KB
    int tid = threadIdx.x;
    int rowbase = blockIdx.x * 32;

    {   // stage X tile (guarded, zero-fill OOB rows)
        const float4* Xv = (const float4*)(X + (size_t)rowbase * 128);
        float4* xsv = (float4*)xs;
        float4 z = make_float4(0.f, 0.f, 0.f, 0.f);
        #pragma unroll 2
        for (int j = 0; j < 4; j++) {
            int i = tid + j * 256;
            int r = rowbase + (i >> 5);
            xsv[i] = (r < N) ? Xv[i] : z;
        }
    }

    int cg = tid & 31;   // col group (4 cols)
    int rq = tid >> 5;   // row quad (4 rows)
    float acc[4][4] = {};

    for (int kb = 0; kb < 128; kb += 64) {
        {   // stage W rows kb..kb+63
            const float4* Wv = (const float4*)(W + kb * 128);
            float4* wsv = (float4*)ws;
            #pragma unroll 2
            for (int i = 0; i < 8; i++) wsv[tid + i * 256] = Wv[tid + i * 256];
        }
        __syncthreads();   // covers ws stage (and xs stage on first iter)

        for (int k = 0; k < 64; k += 4) {
            float4 a[4];
            #pragma unroll
            for (int r = 0; r < 4; r++) a[r] = *(const float4*)&xs[(rq * 4 + r) * 128 + kb + k];
            #pragma unroll
            for (int kk = 0; kk < 4; kk++) {
                float4 b = *(const float4*)&ws[(k + kk) * 128 + cg * 4];
                #pragma unroll
                for (int r = 0; r < 4; r++) {
                    float av = (kk == 0) ? a[r].x : (kk == 1) ? a[r].y : (kk == 2) ? a[r].z : a[r].w;
                    acc[r][0] = fmaf(av, b.x, acc[r][0]);
                    acc[r][1] = fmaf(av, b.y, acc[r][1]);
                    acc[r][2] = fmaf(av, b.z, acc[r][2]);
                    acc[r][3] = fmaf(av, b.w, acc[r][3]);
                }
            }
        }
        __syncthreads();   // before restaging ws
    }

    #pragma unroll
    for (int r = 0; r < 4; r++) {
        int rown = rowbase + rq * 4 + r;
        if (rown < N) {
            float s = dinv[rown];
            float4 o = make_float4(acc[r][0] * s, acc[r][1] * s, acc[r][2] * s, acc[r][3] * s);
            *(float4*)&out[(size_t)rown * 128 + cg * 4] = o;
        }
    }
}

// ---------------- Aggregation (pull mode): one wave per node ----------------
// out[c][:] = relu(dinv[c] * (hs[c][:] + sum_{r in in(c)} hs[r][:]) + bias)
__global__ __launch_bounds__(256, 4) void aggregate_kernel(const float* __restrict__ hs,
                                                           const int* __restrict__ off,
                                                           const int* __restrict__ srclist,
                                                           const float* __restrict__ dinv,
                                                           const float* __restrict__ bias,
                                                           float* __restrict__ out, int N) {
    int wave = (blockIdx.x * 256 + threadIdx.x) >> 6;
    int lane = threadIdx.x & 63;
    if (wave >= N) return;
    int c = wave;
    float2 a0 = *(const float2*)&hs[(size_t)c * 128 + lane * 2];  // self-loop term
    float2 a1 = make_float2(0.f, 0.f);
    float2 a2 = make_float2(0.f, 0.f);
    float2 a3 = make_float2(0.f, 0.f);
    int s0 = off[c], s1 = off[c + 1];
    int i = s0;
    for (; i + 3 < s1; i += 4) {   // 4-deep gather for memory-level parallelism
        int sa = srclist[i], sb = srclist[i + 1], sc = srclist[i + 2], sd = srclist[i + 3];
        float2 va = *(const float2*)&hs[(size_t)sa * 128 + lane * 2];
        float2 vb = *(const float2*)&hs[(size_t)sb * 128 + lane * 2];
        float2 vc = *(const float2*)&hs[(size_t)sc * 128 + lane * 2];
        float2 vd = *(const float2*)&hs[(size_t)sd * 128 + lane * 2];
        a0.x += va.x; a0.y += va.y;
        a1.x += vb.x; a1.y += vb.y;
        a2.x += vc.x; a2.y += vc.y;
        a3.x += vd.x; a3.y += vd.y;
    }
    for (; i < s1; i++) {
        int sa = srclist[i];
        float2 va = *(const float2*)&hs[(size_t)sa * 128 + lane * 2];
        a0.x += va.x; a0.y += va.y;
    }
    a0.x += a1.x + a2.x + a3.x;
    a0.y += a1.y + a2.y + a3.y;
    float d = dinv[c];
    float2 b = *(const float2*)&bias[lane * 2];
    float2 o;
    o.x = fmaxf(fmaf(a0.x, d, b.x), 0.f);
    o.y = fmaxf(fmaf(a0.y, d, b.y), 0.f);
    *(float2*)&out[(size_t)c * 128 + lane * 2] = o;
}

// ---------------- Mean pool over sorted batch ids ----------------
#define POOL_NODES 512
__global__ __launch_bounds__(128) void pool_kernel(const float* __restrict__ h,
                                                   const int* __restrict__ batch,
                                                   float* __restrict__ sums,
                                                   float* __restrict__ cnt, int N) {
    int t = threadIdx.x;  // feature id
    int n0 = blockIdx.x * POOL_NODES;
    if (n0 >= N) return;
    int n1 = min(n0 + POOL_NODES, N);
    int g = batch[n0];
    float acc = 0.f, c = 0.f;
    for (int n = n0; n < n1; n++) {
        int gn = batch[n];  // broadcast load
        if (gn != g) {      // batch sorted -> few flushes per block
            atomicAdd(&sums[g * 128 + t], acc);
            if (t == 0) atomicAdd(&cnt[g], c);
            acc = 0.f; c = 0.f; g = gn;
        }
        acc += h[(size_t)n * 128 + t];
        c += 1.f;
    }
    atomicAdd(&sums[g * 128 + t], acc);
    if (t == 0) atomicAdd(&cnt[g], c);
}

// ---------------- Head: out[g] = dot(sums[g]/max(cnt,1), Wc) + bc ----------------
__global__ __launch_bounds__(64) void head_kernel(const float* __restrict__ sums,
                                                  const float* __restrict__ cnt,
                                                  const float* __restrict__ Wc,
                                                  const float* __restrict__ bc,
                                                  float* __restrict__ out) {
    int g = blockIdx.x, lane = threadIdx.x;
    float c = fmaxf(cnt[g], 1.f);
    float2 s = *(const float2*)&sums[g * 128 + lane * 2];
    float2 w = *(const float2*)&Wc[lane * 2];
    float v = (s.x * w.x + s.y * w.y) / c;
    #pragma unroll
    for (int o = 32; o > 0; o >>= 1) v += __shfl_down(v, o, 64);
    if (lane == 0) out[g] = v + bc[0];
}

extern "C" void kernel_launch(void* const* d_in, const int* in_sizes, int n_in,
                              void* d_out, int out_size, void* d_ws, size_t ws_size,
                              hipStream_t stream) {
    const float* x    = (const float*)d_in[0];
    const int*   edge = (const int*)d_in[1];   // [2][E], row-major
    const int*   batch= (const int*)d_in[2];
    const float* W1   = (const float*)d_in[3];
    const float* b1   = (const float*)d_in[4];
    const float* W2   = (const float*)d_in[5];
    const float* b2   = (const float*)d_in[6];
    const float* Wc   = (const float*)d_in[7];
    const float* bc   = (const float*)d_in[8];
    float* out = (float*)d_out;

    int N = in_sizes[0] / 128;
    int E = in_sizes[1] / 2;
    const int* row = edge;
    const int* col = edge + E;
    int nb = (N + 255) / 256;   // scan chunks

    // workspace: [indeg N][fill N][sums 8192][cnt 64] | bsum | off | dinv | srclist | bufA | bufB
    char* p = (char*)d_ws;
    int*   indeg   = (int*)p;   p += (size_t)N * 4;
    int*   fill    = (int*)p;   p += (size_t)N * 4;
    float* sums    = (float*)p; p += 64 * 128 * 4;
    float* cntg    = (float*)p; p += 64 * 4;
    size_t zero_bytes = (size_t)(p - (char*)d_ws);
    int*   bsum    = (int*)p;   p += (size_t)((nb + 63) & ~63) * 4;
    int*   off     = (int*)p;   p += (size_t)(N + 1) * 4;
    float* dinv    = (float*)p; p += (size_t)N * 4;
    int*   srclist = (int*)p;   p += (size_t)E * 4;
    p = (char*)(((uintptr_t)p + 511) & ~(uintptr_t)511);
    float* bufA    = (float*)p; p += (size_t)N * 128 * 4;
    float* bufB    = (float*)p;

    hipMemsetAsync(d_ws, 0, zero_bytes, stream);  // indeg, fill, sums, cnt

    histogram_kernel<<<(E + 255) / 256, 256, 0, stream>>>(col, indeg, E);
    blocksum_kernel<<<nb, 256, 0, stream>>>(indeg, bsum, N);
    scan_bsums_kernel<<<1, 256, 0, stream>>>(bsum, nb);
    scan_final_kernel<<<nb, 256, 0, stream>>>(indeg, bsum, off, dinv, N, E);
    scatter_csr_kernel<<<(E + 255) / 256, 256, 0, stream>>>(row, col, off, fill, srclist, E);

    // Layer 1
    gemm_scale_kernel<<<(N + 31) / 32, 256, 0, stream>>>(x, W1, dinv, bufA, N);
    aggregate_kernel<<<(N + 3) / 4, 256, 0, stream>>>(bufA, off, srclist, dinv, b1, bufB, N);
    // Layer 2
    gemm_scale_kernel<<<(N + 31) / 32, 256, 0, stream>>>(bufB, W2, dinv, bufA, N);
    aggregate_kernel<<<(N + 3) / 4, 256, 0, stream>>>(bufA, off, srclist, dinv, b2, bufB, N);

    // Pool + head
    pool_kernel<<<(N + POOL_NODES - 1) / POOL_NODES, 128, 0, stream>>>(bufB, batch, sums, cntg, N);
    head_kernel<<<64, 64, 0, stream>>>(sums, cntg, Wc, bc, out);
}

// Round 5
// 389.960 us; speedup vs baseline: 6.6715x; 1.2693x over previous
//
#include <hip/hip_runtime.h>
#include <hip/hip_bf16.h>
#include <stdint.h>

// ---------------- CSR build ----------------

__global__ __launch_bounds__(256) void histogram_kernel(const int* __restrict__ col,
                                                        int* __restrict__ indeg, int E) {
    int i = blockIdx.x * 256 + threadIdx.x;
    if (i < E) atomicAdd(&indeg[col[i]], 1);
}

// Block-wide (256 threads) exclusive scan helper. Returns exclusive prefix of v.
__device__ __forceinline__ int block_excl_scan_256(int v, int tid) {
    int lane = tid & 63, wid = tid >> 6;
    int x = v;
    #pragma unroll
    for (int o = 1; o < 64; o <<= 1) {
        int y = __shfl_up(x, o, 64);
        if (lane >= o) x += y;
    }
    __shared__ int wsum[4];
    if (lane == 63) wsum[wid] = x;
    __syncthreads();
    int base = 0;
    #pragma unroll
    for (int j = 0; j < 4; j++) base += (j < wid) ? wsum[j] : 0;
    return base + x - v;
}

// k1: per-block (256-elem chunk) sums of indeg
__global__ __launch_bounds__(256) void blocksum_kernel(const int* __restrict__ cnt,
                                                       int* __restrict__ bsum, int N) {
    int tid = threadIdx.x;
    int i = blockIdx.x * 256 + tid;
    int v = (i < N) ? cnt[i] : 0;
    int lane = tid & 63, wid = tid >> 6;
    #pragma unroll
    for (int o = 32; o > 0; o >>= 1) v += __shfl_down(v, o, 64);
    __shared__ int ws[4];
    if (lane == 0) ws[wid] = v;
    __syncthreads();
    if (tid == 0) bsum[blockIdx.x] = ws[0] + ws[1] + ws[2] + ws[3];
}

// k2: exclusive scan of bsum[nb] in place (nb <= 256), one block
__global__ __launch_bounds__(256) void scan_bsums_kernel(int* __restrict__ bsum, int nb) {
    int tid = threadIdx.x;
    int v = (tid < nb) ? bsum[tid] : 0;
    int ex = block_excl_scan_256(v, tid);
    if (tid < nb) bsum[tid] = ex;
}

// k3: final offsets + dinv: off[i] = bexcl[blk] + local excl scan; dinv = rsqrt(deg+1)
__global__ __launch_bounds__(256) void scan_final_kernel(const int* __restrict__ cnt,
                                                         const int* __restrict__ bexcl,
                                                         int* __restrict__ off,
                                                         float* __restrict__ dinv,
                                                         int N, int E) {
    int tid = threadIdx.x;
    int i = blockIdx.x * 256 + tid;
    int v = (i < N) ? cnt[i] : 0;
    int ex = block_excl_scan_256(v, tid);
    if (i < N) {
        off[i] = bexcl[blockIdx.x] + ex;
        dinv[i] = rsqrtf((float)(v + 1));   // +1 self-loop; deg>=1 always
    }
    if (blockIdx.x == 0 && tid == 0) off[N] = E;
}

__global__ __launch_bounds__(256) void scatter_csr_kernel(const int* __restrict__ row,
                                                          const int* __restrict__ col,
                                                          const int* __restrict__ off,
                                                          int* __restrict__ fill,
                                                          int* __restrict__ srclist, int E) {
    int i = blockIdx.x * 256 + threadIdx.x;
    if (i < E) {
        int c = col[i];
        int p = atomicAdd(&fill[c], 1);
        srclist[off[c] + p] = row[i];
    }
}

// ---------------- GEMM: out[n][:] = (X[n][:] @ W) * dinv[n] ----------------
// Block: 32 rows x 128 cols, 256 threads, thread = 4 rows x 4 cols.
// W staged in LDS in two 64-row chunks (32 KB each); X tile 16 KB. LDS total 48 KB.
__global__ __launch_bounds__(256, 3) void gemm_scale_kernel(const float* __restrict__ X,
                                                            const float* __restrict__ W,
                                                            const float* __restrict__ dinv,
                                                            float* __restrict__ out, int N) {
    __shared__ float ws[64 * 128];   // 32 KB (one K-chunk of W)
    __shared__ float xs[32 * 128];   // 16 KB
    int tid = threadIdx.x;
    int rowbase = blockIdx.x * 32;

    {   // stage X tile (guarded, zero-fill OOB rows)
        const float4* Xv = (const float4*)(X + (size_t)rowbase * 128);
        float4* xsv = (float4*)xs;
        float4 z = make_float4(0.f, 0.f, 0.f, 0.f);
        #pragma unroll 2
        for (int j = 0; j < 4; j++) {
            int i = tid + j * 256;
            int r = rowbase + (i >> 5);
            xsv[i] = (r < N) ? Xv[i] : z;
        }
    }

    int cg = tid & 31;   // col group (4 cols)
    int rq = tid >> 5;   // row quad (4 rows)
    float acc[4][4] = {};

    for (int kb = 0; kb < 128; kb += 64) {
        {   // stage W rows kb..kb+63
            const float4* Wv = (const float4*)(W + kb * 128);
            float4* wsv = (float4*)ws;
            #pragma unroll 2
            for (int i = 0; i < 8; i++) wsv[tid + i * 256] = Wv[tid + i * 256];
        }
        __syncthreads();   // covers ws stage (and xs stage on first iter)

        for (int k = 0; k < 64; k += 4) {
            float4 a[4];
            #pragma unroll
            for (int r = 0; r < 4; r++) a[r] = *(const float4*)&xs[(rq * 4 + r) * 128 + kb + k];
            #pragma unroll
            for (int kk = 0; kk < 4; kk++) {
                float4 b = *(const float4*)&ws[(k + kk) * 128 + cg * 4];
                #pragma unroll
                for (int r = 0; r < 4; r++) {
                    float av = (kk == 0) ? a[r].x : (kk == 1) ? a[r].y : (kk == 2) ? a[r].z : a[r].w;
                    acc[r][0] = fmaf(av, b.x, acc[r][0]);
                    acc[r][1] = fmaf(av, b.y, acc[r][1]);
                    acc[r][2] = fmaf(av, b.z, acc[r][2]);
                    acc[r][3] = fmaf(av, b.w, acc[r][3]);
                }
            }
        }
        __syncthreads();   // before restaging ws
    }

    #pragma unroll
    for (int r = 0; r < 4; r++) {
        int rown = rowbase + rq * 4 + r;
        if (rown < N) {
            float s = dinv[rown];
            float4 o = make_float4(acc[r][0] * s, acc[r][1] * s, acc[r][2] * s, acc[r][3] * s);
            *(float4*)&out[(size_t)rown * 128 + cg * 4] = o;
        }
    }
}

// ---------------- Aggregation (pull mode): one wave per node ----------------
__global__ __launch_bounds__(256, 4) void aggregate_kernel(const float* __restrict__ hs,
                                                           const int* __restrict__ off,
                                                           const int* __restrict__ srclist,
                                                           const float* __restrict__ dinv,
                                                           const float* __restrict__ bias,
                                                           float* __restrict__ out, int N) {
    int wave = (blockIdx.x * 256 + threadIdx.x) >> 6;
    int lane = threadIdx.x & 63;
    if (wave >= N) return;
    int c = wave;
    float2 a0 = *(const float2*)&hs[(size_t)c * 128 + lane * 2];  // self-loop term
    float2 a1 = make_float2(0.f, 0.f);
    float2 a2 = make_float2(0.f, 0.f);
    float2 a3 = make_float2(0.f, 0.f);
    int s0 = off[c], s1 = off[c + 1];
    int i = s0;
    for (; i + 3 < s1; i += 4) {   // 4-deep gather for memory-level parallelism
        int sa = srclist[i], sb = srclist[i + 1], sc = srclist[i + 2], sd = srclist[i + 3];
        float2 va = *(const float2*)&hs[(size_t)sa * 128 + lane * 2];
        float2 vb = *(const float2*)&hs[(size_t)sb * 128 + lane * 2];
        float2 vc = *(const float2*)&hs[(size_t)sc * 128 + lane * 2];
        float2 vd = *(const float2*)&hs[(size_t)sd * 128 + lane * 2];
        a0.x += va.x; a0.y += va.y;
        a1.x += vb.x; a1.y += vb.y;
        a2.x += vc.x; a2.y += vc.y;
        a3.x += vd.x; a3.y += vd.y;
    }
    for (; i < s1; i++) {
        int sa = srclist[i];
        float2 va = *(const float2*)&hs[(size_t)sa * 128 + lane * 2];
        a0.x += va.x; a0.y += va.y;
    }
    a0.x += a1.x + a2.x + a3.x;
    a0.y += a1.y + a2.y + a3.y;
    float d = dinv[c];
    float2 b = *(const float2*)&bias[lane * 2];
    float2 o;
    o.x = fmaxf(fmaf(a0.x, d, b.x), 0.f);
    o.y = fmaxf(fmaf(a0.y, d, b.y), 0.f);
    *(float2*)&out[(size_t)c * 128 + lane * 2] = o;
}

// ---------------- Fused pool+head partial: per-node dot with Wc, segment-sum ----------------
// out[g] = (sum_{n in g} h[n].Wc) / cnt_g + bc  (pool and head are both linear)
#define PTILE 64
__global__ __launch_bounds__(256) void pool_head_partial(const float* __restrict__ h,
                                                         const int* __restrict__ batch,
                                                         const float* __restrict__ Wc,
                                                         float* __restrict__ gsum,
                                                         float* __restrict__ gcnt, int N) {
    int tid = threadIdx.x;
    int grp = tid >> 5;        // 8 groups of 32 lanes
    int sl  = tid & 31;        // sublane: one float4 of the feature dim
    float4 w = ((const float4*)Wc)[sl];
    int base = blockIdx.x * PTILE;
    int nend = min(base + PTILE, N);
    int gcur = -1;
    float acc = 0.f, cnt = 0.f;
    for (int n = base + grp; n < nend; n += 8) {
        float4 v = *(const float4*)&h[(size_t)n * 128 + sl * 4];
        float d = v.x * w.x + v.y * w.y + v.z * w.z + v.w * w.w;
        #pragma unroll
        for (int o = 16; o > 0; o >>= 1) d += __shfl_xor(d, o, 32);  // all 32 lanes get dot
        int g = batch[n];   // broadcast
        if (g != gcur) {
            if (gcur >= 0 && sl == 0) {
                atomicAdd(&gsum[gcur], acc);
                atomicAdd(&gcnt[gcur], cnt);
            }
            gcur = g; acc = 0.f; cnt = 0.f;
        }
        acc += d; cnt += 1.f;
    }
    if (gcur >= 0 && sl == 0) {
        atomicAdd(&gsum[gcur], acc);
        atomicAdd(&gcnt[gcur], cnt);
    }
}

__global__ __launch_bounds__(64) void head_final(const float* __restrict__ gsum,
                                                 const float* __restrict__ gcnt,
                                                 const float* __restrict__ bc,
                                                 float* __restrict__ out) {
    int g = threadIdx.x;
    out[g] = gsum[g] / fmaxf(gcnt[g], 1.f) + bc[0];
}

extern "C" void kernel_launch(void* const* d_in, const int* in_sizes, int n_in,
                              void* d_out, int out_size, void* d_ws, size_t ws_size,
                              hipStream_t stream) {
    const float* x    = (const float*)d_in[0];
    const int*   edge = (const int*)d_in[1];   // [2][E], row-major
    const int*   batch= (const int*)d_in[2];
    const float* W1   = (const float*)d_in[3];
    const float* b1   = (const float*)d_in[4];
    const float* W2   = (const float*)d_in[5];
    const float* b2   = (const float*)d_in[6];
    const float* Wc   = (const float*)d_in[7];
    const float* bc   = (const float*)d_in[8];
    float* out = (float*)d_out;

    int N = in_sizes[0] / 128;
    int E = in_sizes[1] / 2;
    const int* row = edge;
    const int* col = edge + E;
    int nb = (N + 255) / 256;   // scan chunks

    // workspace: [indeg N][fill N][gsum 64][gcnt 64] | bsum | off | dinv | srclist | bufA | bufB
    char* p = (char*)d_ws;
    int*   indeg   = (int*)p;   p += (size_t)N * 4;
    int*   fill    = (int*)p;   p += (size_t)N * 4;
    float* gsum    = (float*)p; p += 64 * 4;
    float* gcnt    = (float*)p; p += 64 * 4;
    size_t zero_bytes = (size_t)(p - (char*)d_ws);
    int*   bsum    = (int*)p;   p += (size_t)((nb + 63) & ~63) * 4;
    int*   off     = (int*)p;   p += (size_t)(N + 1) * 4;
    float* dinv    = (float*)p; p += (size_t)N * 4;
    int*   srclist = (int*)p;   p += (size_t)E * 4;
    p = (char*)(((uintptr_t)p + 511) & ~(uintptr_t)511);
    float* bufA    = (float*)p; p += (size_t)N * 128 * 4;
    float* bufB    = (float*)p;

    hipMemsetAsync(d_ws, 0, zero_bytes, stream);  // indeg, fill, gsum, gcnt

    histogram_kernel<<<(E + 255) / 256, 256, 0, stream>>>(col, indeg, E);
    blocksum_kernel<<<nb, 256, 0, stream>>>(indeg, bsum, N);
    scan_bsums_kernel<<<1, 256, 0, stream>>>(bsum, nb);
    scan_final_kernel<<<nb, 256, 0, stream>>>(indeg, bsum, off, dinv, N, E);
    scatter_csr_kernel<<<(E + 255) / 256, 256, 0, stream>>>(row, col, off, fill, srclist, E);

    // Layer 1
    gemm_scale_kernel<<<(N + 31) / 32, 256, 0, stream>>>(x, W1, dinv, bufA, N);
    aggregate_kernel<<<(N + 3) / 4, 256, 0, stream>>>(bufA, off, srclist, dinv, b1, bufB, N);
    // Layer 2
    gemm_scale_kernel<<<(N + 31) / 32, 256, 0, stream>>>(bufB, W2, dinv, bufA, N);
    aggregate_kernel<<<(N + 3) / 4, 256, 0, stream>>>(bufA, off, srclist, dinv, b2, bufB, N);

    // Fused pool+head
    pool_head_partial<<<(N + PTILE - 1) / PTILE, 256, 0, stream>>>(bufB, batch, Wc, gsum, gcnt, N);
    head_final<<<1, 64, 0, stream>>>(gsum, gcnt, bc, out);
}